// Round 10
// baseline (56.323 us; speedup 1.0000x reference)
//
#include <hip/hip_runtime.h>
#include <hip/hip_bf16.h>

typedef __attribute__((ext_vector_type(8))) short bf16x8;
typedef __attribute__((ext_vector_type(4))) short s16x4;
typedef __attribute__((ext_vector_type(4))) float fx4;

#define MFMA16(a, b, c) __builtin_amdgcn_mfma_f32_16x16x32_bf16((a), (b), (c), 0, 0, 0)

__device__ __forceinline__ short f2bf(float f) {
  unsigned u = __float_as_uint(f);
  u += 0x7fffu + ((u >> 16) & 1u);   // round-to-nearest-even
  return (short)(u >> 16);
}

// unaligned-tolerant 16B load (V patch reads are only 4B-aligned)
__device__ __forceinline__ bf16x8 ldu16(const short* p) {
  bf16x8 v; __builtin_memcpy(&v, p, 16); return v;
}

// async global->LDS, 16B per lane; LDS dest is wave-uniform base + lane*16B
__device__ __forceinline__ void gl_lds16(const short* g, short* l) {
  __builtin_amdgcn_global_load_lds((const __attribute__((address_space(1))) void*)(g),
                                   (__attribute__((address_space(3))) void*)(l), 16, 0, 0);
}

// ---------------- kernel 0: f32 -> bf16 conversion ----------------
__global__ __launch_bounds__(256) void convert_k(
    const float* __restrict__ x, const float* __restrict__ wq, const float* __restrict__ wo,
    short* __restrict__ xb, short* __restrict__ wb, short* __restrict__ wob) {
  const int i4 = (blockIdx.x * 256 + threadIdx.x) * 4;
  {
    float4 v = *(const float4*)(x + i4);
    s16x4 s; s[0] = f2bf(v.x); s[1] = f2bf(v.y); s[2] = f2bf(v.z); s[3] = f2bf(v.w);
    *(s16x4*)(xb + i4) = s;
  }
  if (i4 < 1152 * 384) {
    float4 v = *(const float4*)(wq + i4);
    s16x4 s; s[0] = f2bf(v.x); s[1] = f2bf(v.y); s[2] = f2bf(v.z); s[3] = f2bf(v.w);
    *(s16x4*)(wb + i4) = s;
  }
  if (i4 < 384 * 384) {
    float4 v = *(const float4*)(wo + i4);
    s16x4 s; s[0] = f2bf(v.x); s[1] = f2bf(v.y); s[2] = f2bf(v.z); s[3] = f2bf(v.w);
    *(s16x4*)(wob + i4) = s;
  }
}

// ---------------- kernel 1: qkv = x @ w_qkv^T, scatter q/k ([pix][d]) and v ([d][pix]) ---
// 128x128 tile, BK=64, XOR-swizzled LDS, DOUBLE-BUFFERED gload_lds pipeline:
// issue loads for t+1 -> compute t (loads fly under MFMA) -> one barrier (drain+reuse guard)
__global__ __launch_bounds__(256) void qkv_gemm(
    const short* __restrict__ A, const short* __restrict__ Bw,
    short* __restrict__ qb, short* __restrict__ kb, short* __restrict__ vb) {
  __shared__ __align__(16) short As[2][128 * 64];   // 2 x 16 KB
  __shared__ __align__(16) short Bs[2][128 * 64];   // 2 x 16 KB  (total 64 KB)
  const int orig = (blockIdx.x & 7) * 72 + (blockIdx.x >> 3);  // 576 = 8*72
  const int mt = orig / 9, nt = orig % 9;
  const int m0 = mt * 128, n0 = nt * 128;
  const int tid = threadIdx.x;
  const int lane = tid & 63, w = tid >> 6;
  const int wr = w >> 1, wc = w & 1;
  const int l15 = lane & 15, l4 = lane >> 4;
  const int srow = lane >> 3;                          // row within 8-row stage group
  const int scol = ((lane & 7) ^ (srow & 7)) * 8;      // inverse-swizzled source col
  const fx4 vzero = {0.f, 0.f, 0.f, 0.f};
  fx4 acc[4][4];
#pragma unroll
  for (int i = 0; i < 4; i++)
#pragma unroll
    for (int j = 0; j < 4; j++) acc[i][j] = vzero;

#define QKV_STAGE(buf, kt)                                                                   \
  _Pragma("unroll")                                                                          \
  for (int q = 0; q < 4; q++) {                                                              \
    gl_lds16(A  + (size_t)(m0 + w * 32 + q * 8 + srow) * 384 + (kt) + scol,                  \
             &As[buf][(w * 32 + q * 8) * 64]);                                               \
    gl_lds16(Bw + (size_t)(n0 + w * 32 + q * 8 + srow) * 384 + (kt) + scol,                  \
             &Bs[buf][(w * 32 + q * 8) * 64]);                                               \
  }

  QKV_STAGE(0, 0)
  __syncthreads();                      // prologue drain (only fully-exposed latency)

  for (int t = 0; t < 6; ++t) {
    if (t < 5) { QKV_STAGE((t + 1) & 1, (t + 1) * 64) }   // issue next-tile loads (async)
    const short* as_c = As[t & 1];
    const short* bs_c = Bs[t & 1];
    bf16x8 af[4][2], bfr[4][2];
#pragma unroll
    for (int i = 0; i < 4; i++) {
      const int ra = wr * 64 + i * 16 + l15;
      const int rb = wc * 64 + i * 16 + l15;
#pragma unroll
      for (int kk = 0; kk < 2; kk++) {
        af[i][kk]  = *(const bf16x8*)(as_c + ra * 64 + (((kk * 4 + l4) ^ (ra & 7)) * 8));
        bfr[i][kk] = *(const bf16x8*)(bs_c + rb * 64 + (((kk * 4 + l4) ^ (rb & 7)) * 8));
      }
    }
#pragma unroll
    for (int i = 0; i < 4; i++)
#pragma unroll
      for (int j = 0; j < 4; j++) {
        acc[i][j] = MFMA16(af[i][0], bfr[j][0], acc[i][j]);
        acc[i][j] = MFMA16(af[i][1], bfr[j][1], acc[i][j]);
      }
    if (t < 5) __syncthreads();         // drains next's loads (mostly done) + reuse guard
  }
  // epilogue: e = t*384 + head*64 + d
  // q,k -> [b][head][pix][64] ; v -> [b][head][64][pix] (d-major, for natt direct loads)
#pragma unroll
  for (int j = 0; j < 4; j++) {
    const int e = n0 + wc * 64 + j * 16 + l15;
    const int t = e / 384;
    const int rem = e - t * 384;
    const int head = rem >> 6, d = rem & 63;
#pragma unroll
    for (int i = 0; i < 4; i++) {
      const int mb = m0 + wr * 64 + i * 16 + l4 * 4;   // multiple of 4
      const int b = mb >> 12, pix = mb & 4095;
      if (t == 2) {
        s16x4 s4;
#pragma unroll
        for (int r = 0; r < 4; r++) s4[r] = f2bf(acc[i][j][r]);
        *(s16x4*)(vb + ((size_t)(b * 6 + head) * 64 + d) * 4096 + pix) = s4;
      } else {
        short* __restrict__ dst = (t == 0) ? qb : kb;
#pragma unroll
        for (int r = 0; r < 4; r++)
          dst[((size_t)(b * 6 + head) * 4096 + pix + r) * 64 + d] = f2bf(acc[i][j][r]);
      }
    }
  }
}

// ---------------- kernel 2: neighbourhood attention ----------------
// K staged in LDS (reused as Ps); V direct from d-major global (hides under softmax/PV).
// LDS 32.3 KB -> 4 blocks/CU; all 768 blocks co-resident in one round.
__global__ __launch_bounds__(256) void natt_k(
    const short* __restrict__ qg, const short* __restrict__ kg, const short* __restrict__ vtg,
    short* __restrict__ ob) {
  __shared__ __align__(16) short lds[224 * 72];  // 32.3 KB; Ks, then reused as Ps
  short* Ks = lds;           // [224][72]  (kk = kr*16+kc, d)
  short* Ps = lds;           // [64][232]  (q, kk)  -- overlays Ks after QK phase

  const int bid = (blockIdx.x & 7) * 96 + (blockIdx.x >> 3);   // 768/8 = 96
  const int tile = bid & 63, bh = bid >> 6;
  const int h0 = (tile >> 3) * 8, w0 = (tile & 7) * 8;
  const int ph0 = max(h0 - 3, 0);
  const int pw0 = min(max(w0 - 3, 0) & ~1, 48);  // even + 16-col slot grid stays in-row
  const int prows = min(h0 + 4, 57) + 7 - ph0;   // <= 14
  const int pcols = min(w0 + 4, 57) + 7 - pw0;   // <= 16
  const short* kb  = kg  + (size_t)bh * 262144;
  const short* vtb = vtg + (size_t)bh * 262144;  // [d][pix]
  const short* qb  = qg  + (size_t)bh * 262144;
  const int tid = threadIdx.x;
  const int lane = tid & 63, w = tid >> 6;
  const int l15 = lane & 15, l4 = lane >> 4;

  // stage K [224][72] (vector writes, adjacent lanes -> contiguous chunks)
  for (int i = tid; i < 224 * 8; i += 256) {
    const int kk = i >> 3, dc = i & 7;
    const int kr = kk >> 4, kc = kk & 15;
    const int krc = min(kr, prows - 1), kcc = min(kc, pcols - 1);
    const int pix = (ph0 + krc) * 64 + (pw0 + kcc);
    *(bf16x8*)(Ks + kk * 72 + dc * 8) = *(const bf16x8*)(kb + pix * 64 + dc * 8);
  }
  __syncthreads();

  // Q fragments straight from global: wave w owns queries [w*16, w*16+16)
  const int qa = w * 16 + l15;
  const int qpix = (h0 + (qa >> 3)) * 64 + (w0 + (qa & 7));
  const bf16x8 aq0 = *(const bf16x8*)(qb + qpix * 64 + l4 * 8);
  const bf16x8 aq1 = *(const bf16x8*)(qb + qpix * 64 + 32 + l4 * 8);

  const fx4 vzero = {0.f, 0.f, 0.f, 0.f};
  fx4 s[14];
#pragma unroll
  for (int n = 0; n < 14; n++) s[n] = vzero;
#pragma unroll
  for (int n = 0; n < 14; n++) {
    const bf16x8 b0 = *(const bf16x8*)(Ks + (n * 16 + l15) * 72 + l4 * 8);
    const bf16x8 b1 = *(const bf16x8*)(Ks + (n * 16 + l15) * 72 + 32 + l4 * 8);
    s[n] = MFMA16(aq0, b0, s[n]);
    s[n] = MFMA16(aq1, b1, s[n]);
  }

  // masked softmax in registers; lane owns rows q = w*16 + l4*4 + r, key col = l15, key row = n
#pragma unroll
  for (int r = 0; r < 4; r++) {
    const int q = w * 16 + l4 * 4 + r;
    const int qh = h0 + (q >> 3), qw = w0 + (q & 7);
    const int sh = min(max(qh - 3, 0), 57) - ph0;
    const int sw = min(max(qw - 3, 0), 57) - pw0;
    float m = -1e30f;
#pragma unroll
    for (int n = 0; n < 14; n++) {
      const bool valid = (n >= sh) && (n < sh + 7) && (l15 >= sw) && (l15 < sw + 7);
      const float val = valid ? s[n][r] * 0.125f : -1e30f;
      s[n][r] = val;
      m = fmaxf(m, val);
    }
    m = fmaxf(m, __shfl_xor(m, 1));
    m = fmaxf(m, __shfl_xor(m, 2));
    m = fmaxf(m, __shfl_xor(m, 4));
    m = fmaxf(m, __shfl_xor(m, 8));
    float sum = 0.f;
#pragma unroll
    for (int n = 0; n < 14; n++) {
      const float e = __expf(s[n][r] - m);
      s[n][r] = e;
      sum += e;
    }
    sum += __shfl_xor(sum, 1);
    sum += __shfl_xor(sum, 2);
    sum += __shfl_xor(sum, 4);
    sum += __shfl_xor(sum, 8);
    const float inv = 1.f / sum;
#pragma unroll
    for (int n = 0; n < 14; n++) s[n][r] *= inv;
  }

  __syncthreads();  // all QK reads of Ks done -> safe to overlay Ps

  // P -> LDS (wave-local rows: wave w writes AND reads only rows [w*16, w*16+16))
#pragma unroll
  for (int n = 0; n < 14; n++)
#pragma unroll
    for (int r = 0; r < 4; r++)
      Ps[(w * 16 + l4 * 4 + r) * 232 + n * 16 + l15] = f2bf(s[n][r]);

  __builtin_amdgcn_wave_barrier();

  // PV: V fragments direct from d-major global [d][pix]; reads always in-row (pw0<=48)
  fx4 o[4];
#pragma unroll
  for (int j = 0; j < 4; j++) o[j] = vzero;
#pragma unroll
  for (int ks = 0; ks < 7; ks++) {
    const bf16x8 pa = *(const bf16x8*)(Ps + (w * 16 + l15) * 232 + ks * 32 + l4 * 8);
    const int kr = 2 * ks + (l4 >> 1);
    const int vp = (ph0 + min(kr, prows - 1)) * 64 + pw0 + (l4 & 1) * 8;
#pragma unroll
    for (int j = 0; j < 4; j++) {
      const bf16x8 vf = ldu16(vtb + (size_t)(j * 16 + l15) * 4096 + vp);
      o[j] = MFMA16(pa, vf, o[j]);
    }
  }

  const int b = bh / 6, head = bh % 6;
#pragma unroll
  for (int j = 0; j < 4; j++) {
    const int d = j * 16 + l15;
#pragma unroll
    for (int r = 0; r < 4; r++) {
      const int q = w * 16 + l4 * 4 + r;
      const int pix = (h0 + (q >> 3)) * 64 + (w0 + (q & 7));
      ob[(size_t)(b * 4096 + pix) * 384 + head * 64 + d] = f2bf(o[j][r]);
    }
  }
}

// ---------------- kernel 3: out = attn_out @ w_out^T (f32 output) ----------------
// 64x64 tile, 768 blocks (3/CU), BK=64, swizzled, double-buffered gload_lds pipeline
__global__ __launch_bounds__(256) void out_gemm(
    const short* __restrict__ A, const short* __restrict__ Bw, float* __restrict__ out) {
  __shared__ __align__(16) short As[2][64 * 64];   // 2 x 8 KB
  __shared__ __align__(16) short Bs[2][64 * 64];   // 2 x 8 KB (total 32 KB)
  const int orig = (blockIdx.x & 7) * 96 + (blockIdx.x >> 3);  // 768 = 8*96
  const int mt = orig / 6, nt = orig % 6;
  const int m0 = mt * 64, n0 = nt * 64;
  const int tid = threadIdx.x;
  const int lane = tid & 63, w = tid >> 6;
  const int wr = w >> 1, wc = w & 1;        // wave: 32 rows x 32 cols
  const int l15 = lane & 15, l4 = lane >> 4;
  const int srow = lane >> 3;
  const int scol = ((lane & 7) ^ (srow & 7)) * 8;
  const fx4 vzero = {0.f, 0.f, 0.f, 0.f};
  fx4 acc[2][2];
#pragma unroll
  for (int i = 0; i < 2; i++)
#pragma unroll
    for (int j = 0; j < 2; j++) acc[i][j] = vzero;

#define OUT_STAGE(buf, kt)                                                                   \
  _Pragma("unroll")                                                                          \
  for (int q = 0; q < 2; q++) {                                                              \
    gl_lds16(A  + (size_t)(m0 + w * 16 + q * 8 + srow) * 384 + (kt) + scol,                  \
             &As[buf][(w * 16 + q * 8) * 64]);                                               \
    gl_lds16(Bw + (size_t)(n0 + w * 16 + q * 8 + srow) * 384 + (kt) + scol,                  \
             &Bs[buf][(w * 16 + q * 8) * 64]);                                               \
  }

  OUT_STAGE(0, 0)
  __syncthreads();

  for (int t = 0; t < 6; ++t) {
    if (t < 5) { OUT_STAGE((t + 1) & 1, (t + 1) * 64) }
    const short* as_c = As[t & 1];
    const short* bs_c = Bs[t & 1];
    bf16x8 af[2][2], bfr[2][2];
#pragma unroll
    for (int i = 0; i < 2; i++) {
      const int ra = wr * 32 + i * 16 + l15;
#pragma unroll
      for (int kk = 0; kk < 2; kk++)
        af[i][kk] = *(const bf16x8*)(as_c + ra * 64 + (((kk * 4 + l4) ^ (ra & 7)) * 8));
    }
#pragma unroll
    for (int j = 0; j < 2; j++) {
      const int rb = wc * 32 + j * 16 + l15;
#pragma unroll
      for (int kk = 0; kk < 2; kk++)
        bfr[j][kk] = *(const bf16x8*)(bs_c + rb * 64 + (((kk * 4 + l4) ^ (rb & 7)) * 8));
    }
#pragma unroll
    for (int i = 0; i < 2; i++)
#pragma unroll
      for (int j = 0; j < 2; j++) {
        acc[i][j] = MFMA16(af[i][0], bfr[j][0], acc[i][j]);
        acc[i][j] = MFMA16(af[i][1], bfr[j][1], acc[i][j]);
      }
    if (t < 5) __syncthreads();
  }
#pragma unroll
  for (int j = 0; j < 2; j++) {
    const int e = n0 + wc * 32 + j * 16 + l15;
#pragma unroll
    for (int i = 0; i < 2; i++) {
      const int mb = m0 + wr * 32 + i * 16 + l4 * 4;
#pragma unroll
      for (int r = 0; r < 4; r++)
        out[(size_t)(mb + r) * 384 + e] = acc[i][j][r];
    }
  }
}

extern "C" void kernel_launch(void* const* d_in, const int* in_sizes, int n_in,
                              void* d_out, int out_size, void* d_ws, size_t ws_size,
                              hipStream_t stream) {
  const float* x  = (const float*)d_in[0];
  const float* wq = (const float*)d_in[1];
  const float* wo = (const float*)d_in[2];
  float* out = (float*)d_out;

  short* xb  = (short*)d_ws;            // 8192*384
  short* wb  = xb + 8192 * 384;         // 1152*384
  short* wob = wb + 1152 * 384;         // 384*384
  short* qb  = wob + 384 * 384;         // 12*4096*64
  short* kb  = qb + 3145728;
  short* vb  = kb + 3145728;            // v in [b][head][64][4096] (d-major)
  short* ob  = vb + 3145728;            // 8192*384
  // total: ~32.6 MB of d_ws

  convert_k<<<3072, 256, 0, stream>>>(x, wq, wo, xb, wb, wob);
  qkv_gemm<<<576, 256, 0, stream>>>(xb, wb, qb, kb, vb);
  natt_k<<<768, 256, 0, stream>>>(qb, kb, vb, ob);
  out_gemm<<<768, 256, 0, stream>>>(ob, wob, out);
}

// Round 11
// 45.876 us; speedup vs baseline: 1.2277x; 1.2277x over previous
//
#include <hip/hip_runtime.h>
#include <hip/hip_bf16.h>

typedef __attribute__((ext_vector_type(8))) short bf16x8;
typedef __attribute__((ext_vector_type(4))) short s16x4;
typedef __attribute__((ext_vector_type(4))) float fx4;

#define MFMA16(a, b, c) __builtin_amdgcn_mfma_f32_16x16x32_bf16((a), (b), (c), 0, 0, 0)

__device__ __forceinline__ short f2bf(float f) {
  unsigned u = __float_as_uint(f);
  u += 0x7fffu + ((u >> 16) & 1u);   // round-to-nearest-even
  return (short)(u >> 16);
}

// unaligned-tolerant 16B load (V patch reads are only 4B-aligned)
__device__ __forceinline__ bf16x8 ldu16(const short* p) {
  bf16x8 v; __builtin_memcpy(&v, p, 16); return v;
}

// async global->LDS, 16B per lane; LDS dest is wave-uniform base + lane*16B
__device__ __forceinline__ void gl_lds16(const short* g, short* l) {
  __builtin_amdgcn_global_load_lds((const __attribute__((address_space(1))) void*)(g),
                                   (__attribute__((address_space(3))) void*)(l), 16, 0, 0);
}

// ---------------- kernel 0: f32 -> bf16 conversion ----------------
__global__ __launch_bounds__(256) void convert_k(
    const float* __restrict__ x, const float* __restrict__ wq, const float* __restrict__ wo,
    short* __restrict__ xb, short* __restrict__ wb, short* __restrict__ wob) {
  const int i4 = (blockIdx.x * 256 + threadIdx.x) * 4;
  {
    float4 v = *(const float4*)(x + i4);
    s16x4 s; s[0] = f2bf(v.x); s[1] = f2bf(v.y); s[2] = f2bf(v.z); s[3] = f2bf(v.w);
    *(s16x4*)(xb + i4) = s;
  }
  if (i4 < 1152 * 384) {
    float4 v = *(const float4*)(wq + i4);
    s16x4 s; s[0] = f2bf(v.x); s[1] = f2bf(v.y); s[2] = f2bf(v.z); s[3] = f2bf(v.w);
    *(s16x4*)(wb + i4) = s;
  }
  if (i4 < 384 * 384) {
    float4 v = *(const float4*)(wo + i4);
    s16x4 s; s[0] = f2bf(v.x); s[1] = f2bf(v.y); s[2] = f2bf(v.z); s[3] = f2bf(v.w);
    *(s16x4*)(wob + i4) = s;
  }
}

// ---------------- kernel 1: qkv = x @ w_qkv^T, scatter q/k ([pix][d]) and v ([d][pix]) ---
// 128x128 tile, BK=64, XOR-swizzled LDS (pre-swizzled global src + swizzled read)
__global__ __launch_bounds__(256) void qkv_gemm(
    const short* __restrict__ A, const short* __restrict__ Bw,
    short* __restrict__ qb, short* __restrict__ kb, short* __restrict__ vb) {
  __shared__ __align__(16) short As[128 * 64];   // 16 KB
  __shared__ __align__(16) short Bs[128 * 64];   // 16 KB
  const int orig = (blockIdx.x & 7) * 72 + (blockIdx.x >> 3);  // 576 = 8*72
  const int mt = orig / 9, nt = orig % 9;
  const int m0 = mt * 128, n0 = nt * 128;
  const int tid = threadIdx.x;
  const int lane = tid & 63, w = tid >> 6;
  const int wr = w >> 1, wc = w & 1;
  const int l15 = lane & 15, l4 = lane >> 4;
  const int srow = lane >> 3;                          // row within 8-row stage group
  const int scol = ((lane & 7) ^ (srow & 7)) * 8;      // inverse-swizzled source col
  const fx4 vzero = {0.f, 0.f, 0.f, 0.f};
  fx4 acc[4][4];
#pragma unroll
  for (int i = 0; i < 4; i++)
#pragma unroll
    for (int j = 0; j < 4; j++) acc[i][j] = vzero;

  for (int kt = 0; kt < 384; kt += 64) {
    __syncthreads();
    // wave w stages rows [w*32, w*32+32) of A and B (8 rows per gload)
#pragma unroll
    for (int q = 0; q < 4; q++) {
      gl_lds16(A  + (size_t)(m0 + w * 32 + q * 8 + srow) * 384 + kt + scol, As + (w * 32 + q * 8) * 64);
      gl_lds16(Bw + (size_t)(n0 + w * 32 + q * 8 + srow) * 384 + kt + scol, Bs + (w * 32 + q * 8) * 64);
    }
    __syncthreads();
    bf16x8 af[4][2], bfr[4][2];
#pragma unroll
    for (int i = 0; i < 4; i++) {
      const int ra = wr * 64 + i * 16 + l15;
      const int rb = wc * 64 + i * 16 + l15;
#pragma unroll
      for (int kk = 0; kk < 2; kk++) {
        af[i][kk]  = *(const bf16x8*)(As + ra * 64 + (((kk * 4 + l4) ^ (ra & 7)) * 8));
        bfr[i][kk] = *(const bf16x8*)(Bs + rb * 64 + (((kk * 4 + l4) ^ (rb & 7)) * 8));
      }
    }
#pragma unroll
    for (int i = 0; i < 4; i++)
#pragma unroll
      for (int j = 0; j < 4; j++) {
        acc[i][j] = MFMA16(af[i][0], bfr[j][0], acc[i][j]);
        acc[i][j] = MFMA16(af[i][1], bfr[j][1], acc[i][j]);
      }
  }
  // epilogue: e = t*384 + head*64 + d
  // q,k -> [b][head][pix][64] ; v -> [b][head][64][pix] (d-major, for natt direct loads)
#pragma unroll
  for (int j = 0; j < 4; j++) {
    const int e = n0 + wc * 64 + j * 16 + l15;
    const int t = e / 384;
    const int rem = e - t * 384;
    const int head = rem >> 6, d = rem & 63;
#pragma unroll
    for (int i = 0; i < 4; i++) {
      const int mb = m0 + wr * 64 + i * 16 + l4 * 4;   // multiple of 4
      const int b = mb >> 12, pix = mb & 4095;
      if (t == 2) {
        s16x4 s4;
#pragma unroll
        for (int r = 0; r < 4; r++) s4[r] = f2bf(acc[i][j][r]);
        *(s16x4*)(vb + ((size_t)(b * 6 + head) * 64 + d) * 4096 + pix) = s4;
      } else {
        short* __restrict__ dst = (t == 0) ? qb : kb;
#pragma unroll
        for (int r = 0; r < 4; r++)
          dst[((size_t)(b * 6 + head) * 4096 + pix + r) * 64 + d] = f2bf(acc[i][j][r]);
      }
    }
  }
}

// ---------------- kernel 2: neighbourhood attention ----------------
// K staged in LDS (reused as Ps); V direct from d-major global.
// Per-wave key-row window: wave w's 16 queries (2 image rows) need only 8 consecutive
// patch rows [nlo, nlo+7] -> QK/PV MFMAs 28->16 each, softmax loops 14->8.
__global__ __launch_bounds__(256) void natt_k(
    const short* __restrict__ qg, const short* __restrict__ kg, const short* __restrict__ vtg,
    short* __restrict__ ob) {
  __shared__ __align__(16) short lds[224 * 72];  // 32.3 KB; Ks, then reused as Ps
  short* Ks = lds;           // [224][72]  (kk = kr*16+kc, d)
  short* Ps = lds;           // [64][136]  (q, local slot) -- overlays Ks after QK phase

  const int bid = (blockIdx.x & 7) * 96 + (blockIdx.x >> 3);   // 768/8 = 96
  const int tile = bid & 63, bh = bid >> 6;
  const int h0 = (tile >> 3) * 8, w0 = (tile & 7) * 8;
  const int ph0 = max(h0 - 3, 0);
  const int pw0 = min(max(w0 - 3, 0) & ~1, 48);  // even + 16-col slot grid stays in-row
  const int prows = min(h0 + 4, 57) + 7 - ph0;   // <= 14
  const int pcols = min(w0 + 4, 57) + 7 - pw0;   // <= 16
  const short* kb  = kg  + (size_t)bh * 262144;
  const short* vtb = vtg + (size_t)bh * 262144;  // [d][pix]
  const short* qb  = qg  + (size_t)bh * 262144;
  const int tid = threadIdx.x;
  const int lane = tid & 63, w = tid >> 6;
  const int l15 = lane & 15, l4 = lane >> 4;

  // wave's key-row window start: sh evaluated at query row 2w (wave-uniform)
  const int nlo = min(max(h0 + 2 * w - 3, 0), 57) - ph0;

  // stage K [224][72] (vector writes, adjacent lanes -> contiguous chunks)
  for (int i = tid; i < 224 * 8; i += 256) {
    const int kk = i >> 3, dc = i & 7;
    const int kr = kk >> 4, kc = kk & 15;
    const int krc = min(kr, prows - 1), kcc = min(kc, pcols - 1);
    const int pix = (ph0 + krc) * 64 + (pw0 + kcc);
    *(bf16x8*)(Ks + kk * 72 + dc * 8) = *(const bf16x8*)(kb + pix * 64 + dc * 8);
  }
  __syncthreads();

  // Q fragments straight from global: wave w owns queries [w*16, w*16+16)
  const int qa = w * 16 + l15;
  const int qpix = (h0 + (qa >> 3)) * 64 + (w0 + (qa & 7));
  const bf16x8 aq0 = *(const bf16x8*)(qb + qpix * 64 + l4 * 8);
  const bf16x8 aq1 = *(const bf16x8*)(qb + qpix * 64 + 32 + l4 * 8);

  const fx4 vzero = {0.f, 0.f, 0.f, 0.f};
  fx4 s[8];
#pragma unroll
  for (int nj = 0; nj < 8; nj++) s[nj] = vzero;
#pragma unroll
  for (int nj = 0; nj < 8; nj++) {
    const int n = nlo + nj;
    const bf16x8 b0 = *(const bf16x8*)(Ks + (n * 16 + l15) * 72 + l4 * 8);
    const bf16x8 b1 = *(const bf16x8*)(Ks + (n * 16 + l15) * 72 + 32 + l4 * 8);
    s[nj] = MFMA16(aq0, b0, s[nj]);
    s[nj] = MFMA16(aq1, b1, s[nj]);
  }

  // masked softmax in registers; lane owns rows q = w*16 + l4*4 + r, key col = l15
#pragma unroll
  for (int r = 0; r < 4; r++) {
    const int q = w * 16 + l4 * 4 + r;
    const int qh = h0 + (q >> 3), qw = w0 + (q & 7);
    const int sh = min(max(qh - 3, 0), 57) - ph0;
    const int sw = min(max(qw - 3, 0), 57) - pw0;
    float m = -1e30f;
#pragma unroll
    for (int nj = 0; nj < 8; nj++) {
      const int n = nlo + nj;
      const bool valid = (n >= sh) && (n < sh + 7) && (l15 >= sw) && (l15 < sw + 7);
      const float val = valid ? s[nj][r] * 0.125f : -1e30f;
      s[nj][r] = val;
      m = fmaxf(m, val);
    }
    m = fmaxf(m, __shfl_xor(m, 1));
    m = fmaxf(m, __shfl_xor(m, 2));
    m = fmaxf(m, __shfl_xor(m, 4));
    m = fmaxf(m, __shfl_xor(m, 8));
    float sum = 0.f;
#pragma unroll
    for (int nj = 0; nj < 8; nj++) {
      const float e = __expf(s[nj][r] - m);
      s[nj][r] = e;
      sum += e;
    }
    sum += __shfl_xor(sum, 1);
    sum += __shfl_xor(sum, 2);
    sum += __shfl_xor(sum, 4);
    sum += __shfl_xor(sum, 8);
    const float inv = 1.f / sum;
#pragma unroll
    for (int nj = 0; nj < 8; nj++) s[nj][r] *= inv;
  }

  __syncthreads();  // all QK reads of Ks done -> safe to overlay Ps

  // P -> LDS, local slot index (wave-local rows: wave w touches only rows [w*16, w*16+16))
#pragma unroll
  for (int nj = 0; nj < 8; nj++)
#pragma unroll
    for (int r = 0; r < 4; r++)
      Ps[(w * 16 + l4 * 4 + r) * 136 + nj * 16 + l15] = f2bf(s[nj][r]);

  __builtin_amdgcn_wave_barrier();

  // PV: V fragments direct from d-major global [d][pix]; local slot -> row nlo + (sl>>4)
  fx4 o[4];
#pragma unroll
  for (int j = 0; j < 4; j++) o[j] = vzero;
#pragma unroll
  for (int ks = 0; ks < 4; ks++) {
    const bf16x8 pa = *(const bf16x8*)(Ps + (w * 16 + l15) * 136 + ks * 32 + l4 * 8);
    const int n = nlo + 2 * ks + (l4 >> 1);
    const int vp = (ph0 + min(n, prows - 1)) * 64 + pw0 + (l4 & 1) * 8;
#pragma unroll
    for (int j = 0; j < 4; j++) {
      const bf16x8 vf = ldu16(vtb + (size_t)(j * 16 + l15) * 4096 + vp);
      o[j] = MFMA16(pa, vf, o[j]);
    }
  }

  const int b = bh / 6, head = bh % 6;
#pragma unroll
  for (int j = 0; j < 4; j++) {
    const int d = j * 16 + l15;
#pragma unroll
    for (int r = 0; r < 4; r++) {
      const int q = w * 16 + l4 * 4 + r;
      const int pix = (h0 + (q >> 3)) * 64 + (w0 + (q & 7));
      ob[(size_t)(b * 4096 + pix) * 384 + head * 64 + d] = f2bf(o[j][r]);
    }
  }
}

// ---------------- kernel 3: out = attn_out @ w_out^T (f32 output) ----------------
// 64x64 tile -> 768 blocks (exactly 3/CU, no tail round), BK=64, swizzled gload_lds
__global__ __launch_bounds__(256) void out_gemm(
    const short* __restrict__ A, const short* __restrict__ Bw, float* __restrict__ out) {
  __shared__ __align__(16) short As[64 * 64];    // 8 KB
  __shared__ __align__(16) short Bs[64 * 64];    // 8 KB
  const int orig = (blockIdx.x & 7) * 96 + (blockIdx.x >> 3);  // 768 = 8*96
  const int mt = orig / 6, nt = orig % 6;
  const int m0 = mt * 64, n0 = nt * 64;
  const int tid = threadIdx.x;
  const int lane = tid & 63, w = tid >> 6;
  const int wr = w >> 1, wc = w & 1;        // wave: 32 rows x 32 cols
  const int l15 = lane & 15, l4 = lane >> 4;
  const int srow = lane >> 3;
  const int scol = ((lane & 7) ^ (srow & 7)) * 8;
  const fx4 vzero = {0.f, 0.f, 0.f, 0.f};
  fx4 acc[2][2];
#pragma unroll
  for (int i = 0; i < 2; i++)
#pragma unroll
    for (int j = 0; j < 2; j++) acc[i][j] = vzero;

  for (int kt = 0; kt < 384; kt += 64) {
    __syncthreads();
#pragma unroll
    for (int q = 0; q < 2; q++) {
      gl_lds16(A  + (size_t)(m0 + w * 16 + q * 8 + srow) * 384 + kt + scol, As + (w * 16 + q * 8) * 64);
      gl_lds16(Bw + (size_t)(n0 + w * 16 + q * 8 + srow) * 384 + kt + scol, Bs + (w * 16 + q * 8) * 64);
    }
    __syncthreads();
    bf16x8 af[2][2], bfr[2][2];
#pragma unroll
    for (int i = 0; i < 2; i++) {
      const int ra = wr * 32 + i * 16 + l15;
#pragma unroll
      for (int kk = 0; kk < 2; kk++)
        af[i][kk] = *(const bf16x8*)(As + ra * 64 + (((kk * 4 + l4) ^ (ra & 7)) * 8));
    }
#pragma unroll
    for (int j = 0; j < 2; j++) {
      const int rb = wc * 32 + j * 16 + l15;
#pragma unroll
      for (int kk = 0; kk < 2; kk++)
        bfr[j][kk] = *(const bf16x8*)(Bs + rb * 64 + (((kk * 4 + l4) ^ (rb & 7)) * 8));
    }
#pragma unroll
    for (int i = 0; i < 2; i++)
#pragma unroll
      for (int j = 0; j < 2; j++) {
        acc[i][j] = MFMA16(af[i][0], bfr[j][0], acc[i][j]);
        acc[i][j] = MFMA16(af[i][1], bfr[j][1], acc[i][j]);
      }
  }
#pragma unroll
  for (int j = 0; j < 2; j++) {
    const int e = n0 + wc * 32 + j * 16 + l15;
#pragma unroll
    for (int i = 0; i < 2; i++) {
      const int mb = m0 + wr * 32 + i * 16 + l4 * 4;
#pragma unroll
      for (int r = 0; r < 4; r++)
        out[(size_t)(mb + r) * 384 + e] = acc[i][j][r];
    }
  }
}

extern "C" void kernel_launch(void* const* d_in, const int* in_sizes, int n_in,
                              void* d_out, int out_size, void* d_ws, size_t ws_size,
                              hipStream_t stream) {
  const float* x  = (const float*)d_in[0];
  const float* wq = (const float*)d_in[1];
  const float* wo = (const float*)d_in[2];
  float* out = (float*)d_out;

  short* xb  = (short*)d_ws;            // 8192*384
  short* wb  = xb + 8192 * 384;         // 1152*384
  short* wob = wb + 1152 * 384;         // 384*384
  short* qb  = wob + 384 * 384;         // 12*4096*64
  short* kb  = qb + 3145728;
  short* vb  = kb + 3145728;            // v in [b][head][64][4096] (d-major)
  short* ob  = vb + 3145728;            // 8192*384
  // total: ~32.6 MB of d_ws

  convert_k<<<3072, 256, 0, stream>>>(x, wq, wo, xb, wb, wob);
  qkv_gemm<<<576, 256, 0, stream>>>(xb, wb, qb, kb, vb);
  natt_k<<<768, 256, 0, stream>>>(qb, kb, vb, ob);
  out_gemm<<<768, 256, 0, stream>>>(ob, wob, out);
}